// Round 5
// baseline (118.228 us; speedup 1.0000x reference)
//
#include <hip/hip_runtime.h>
#include <hip/hip_bf16.h>
#include <cstdint>

// ---------------------------------------------------------------------------
// Fused causal self-attention block (B=2, T=2048, C=1024, H=16, Dh=64), fp32 in/out.
// cvt fp32->bf16 -> QKV GEMM (Q pre-scaled) -> V-transpose -> causal flash attn -> out GEMM.
// Workspace (48MB):
//   xb/Vt @ 0     8 MB   bf16 x [4096][1024]; REUSED after gemm1 as Vt [32][64][2048]
//   wqkvb @ 8 MB  6 MB   bf16 w_qkv [3072][1024]
//   wob   @ 14MB  2 MB   bf16 w_out [1024][1024]
//   qkvb  @ 16MB 24 MB   bf16 qkv [4096][3072] (Q|K|V per row; Q scaled by 0.125*log2e)
//   yb    @ 40MB  8 MB   bf16 attn out [4096][1024]
// ---------------------------------------------------------------------------

typedef __bf16 bf16x8 __attribute__((ext_vector_type(8)));
typedef __bf16 bf16x2 __attribute__((ext_vector_type(2)));
typedef float  f32x4  __attribute__((ext_vector_type(4)));

#define EMB   1024
#define HEADS 16
#define HD    64
#define TT    2048
#define NROWS 4096
#define QKVN  3072
#define SCL   0.18033688f   /* 0.125 * log2(e): folded into Q at gemm1 epilogue */
#define THR   11.0f         /* defer-max threshold, log2 units */

// ---- fused fp32 -> bf16 (8 elems / thread, 3 arrays in one launch) ----
__global__ void cvt_all(const float* __restrict__ x, const float* __restrict__ wq,
                        const float* __restrict__ wo, __bf16* __restrict__ xb,
                        __bf16* __restrict__ wqb, __bf16* __restrict__ wob) {
  const int bid = blockIdx.x;
  const float* in; __bf16* out; int i;
  if (bid < 2048)      { in = x;  out = xb;  i = bid * 256 + threadIdx.x; }
  else if (bid < 3584) { in = wq; out = wqb; i = (bid - 2048) * 256 + threadIdx.x; }
  else                 { in = wo; out = wob; i = (bid - 3584) * 256 + threadIdx.x; }
  const float4* p = (const float4*)in + (size_t)i * 2;
  float4 a = p[0], b = p[1];
  bf16x8 o;
  o[0] = (__bf16)a.x; o[1] = (__bf16)a.y; o[2] = (__bf16)a.z; o[3] = (__bf16)a.w;
  o[4] = (__bf16)b.x; o[5] = (__bf16)b.y; o[6] = (__bf16)b.z; o[7] = (__bf16)b.w;
  *((bf16x8*)out + i) = o;
}

__device__ __forceinline__ void gload_lds16(const void* g, void* l) {
  __builtin_amdgcn_global_load_lds(
      (const __attribute__((address_space(1))) void*)(uintptr_t)g,
      (__attribute__((address_space(3))) void*)(uint32_t)(uintptr_t)l,
      16, 0, 0);
}

// ---- GEMM: C[M,N] = A[M,K] * Bm[N,K]^T (m97 structure + XCD swizzle) ----
// SCALE_Q: multiply columns < EMB by SCL before store (Q pre-scale for attn).
template <int OUT_BF16, int SCALE_Q>
__global__ __launch_bounds__(256, 2)
void gemm_bt(const __bf16* __restrict__ A, const __bf16* __restrict__ Bm,
             void* __restrict__ Cout, int M, int N, int K) {
  __shared__ __align__(16) __bf16 As[128 * 32];
  __shared__ __align__(16) __bf16 Bs[128 * 32];
  const int tid  = threadIdx.x;
  const int lane = tid & 63;
  const int wid  = tid >> 6;
  const int wr = wid >> 1, wc = wid & 1;
  const int nwg = gridDim.x * gridDim.y;
  int flat = blockIdx.y * gridDim.x + blockIdx.x;
  flat = (flat & 7) * (nwg >> 3) + (flat >> 3);
  const int brow = (flat / gridDim.x) * 128;
  const int bcol = (flat % gridDim.x) * 128;
  const int fr = lane & 15, g = lane >> 4;

  f32x4 acc[4][4];
#pragma unroll
  for (int m = 0; m < 4; m++)
#pragma unroll
    for (int n = 0; n < 4; n++)
#pragma unroll
      for (int r = 0; r < 4; r++) acc[m][n][r] = 0.0f;

  const int c0 = tid, c1 = tid + 256;
  for (int k0 = 0; k0 < K; k0 += 32) {
    __syncthreads();
    gload_lds16(A  + (size_t)(brow + (c0 >> 2)) * K + k0 + (c0 & 3) * 8, (char*)As + c0 * 16);
    gload_lds16(A  + (size_t)(brow + (c1 >> 2)) * K + k0 + (c1 & 3) * 8, (char*)As + c1 * 16);
    gload_lds16(Bm + (size_t)(bcol + (c0 >> 2)) * K + k0 + (c0 & 3) * 8, (char*)Bs + c0 * 16);
    gload_lds16(Bm + (size_t)(bcol + (c1 >> 2)) * K + k0 + (c1 & 3) * 8, (char*)Bs + c1 * 16);
    __syncthreads();

    bf16x8 af[4], bfr[4];
#pragma unroll
    for (int m = 0; m < 4; m++)
      af[m] = *(const bf16x8*)((const char*)As + (wr * 64 + m * 16 + fr) * 64 + g * 16);
#pragma unroll
    for (int n = 0; n < 4; n++)
      bfr[n] = *(const bf16x8*)((const char*)Bs + (wc * 64 + n * 16 + fr) * 64 + g * 16);
#pragma unroll
    for (int m = 0; m < 4; m++)
#pragma unroll
      for (int n = 0; n < 4; n++)
        acc[m][n] = __builtin_amdgcn_mfma_f32_16x16x32_bf16(af[m], bfr[n], acc[m][n], 0, 0, 0);
  }

  const float qscale = (SCALE_Q && bcol < EMB) ? SCL : 1.0f;
  const int rbase = brow + wr * 64 + g * 4;
  const int cbase = bcol + wc * 64 + fr;
#pragma unroll
  for (int m = 0; m < 4; m++)
#pragma unroll
    for (int n = 0; n < 4; n++) {
      const int col = cbase + n * 16;
#pragma unroll
      for (int r = 0; r < 4; r++) {
        const int row = rbase + m * 16 + r;
        const float v = acc[m][n][r] * qscale;
        if (OUT_BF16) ((__bf16*)Cout)[(size_t)row * N + col] = (__bf16)v;
        else          ((float*)Cout)[(size_t)row * N + col]  = v;
      }
    }
}

// ---- V transpose: qkv [4096][3072] (V cols) -> Vt [32 bh][64 d][2048 t] ----
__global__ __launch_bounds__(256)
void vtrans(const __bf16* __restrict__ qkv, __bf16* __restrict__ vt) {
  __shared__ __bf16 tile[64][66];
  const int tt = blockIdx.x;
  const int bh = blockIdx.y;
  const int b = bh >> 4, h = bh & 15;
  const int tid = threadIdx.x;
  const int tl = tid >> 2, dq = (tid & 3) * 16;
  const __bf16* src = qkv + ((size_t)(b * TT + tt * 64 + tl)) * QKVN + 2 * EMB + h * HD + dq;
  bf16x8 v0 = *(const bf16x8*)src;
  bf16x8 v1 = *(const bf16x8*)(src + 8);
#pragma unroll
  for (int u = 0; u < 4; u++) {
    *(bf16x2*)&tile[tl][dq + 2 * u]     = bf16x2{v0[2 * u], v0[2 * u + 1]};
    *(bf16x2*)&tile[tl][dq + 8 + 2 * u] = bf16x2{v1[2 * u], v1[2 * u + 1]};
  }
  __syncthreads();
  const int d = tid >> 2, tc = (tid & 3) * 16;
  bf16x8 o0, o1;
#pragma unroll
  for (int j = 0; j < 8; j++) { o0[j] = tile[tc + j][d]; o1[j] = tile[tc + 8 + j][d]; }
  __bf16* dst = vt + ((size_t)bh * HD + d) * TT + tt * 64 + tc;
  *(bf16x8*)dst = o0;
  *(bf16x8*)(dst + 8) = o1;
}

// ---------------------------------------------------------------------------
// Causal flash attention v5: uniform-work blocks. Block = chunk pair (c, 31-c),
// 4 waves; each wave owns 16 rows of chunk c AND 16 rows of chunk 31-c.
// Every block does exactly 33 q-tile units -> flat occupancy, no tail.
// Shared kf/vb LDS fragment reads feed both row-groups (DS per work halved).
// K and Vt direct gload_lds (source-swizzled, linear dest), double-buffered,
// one barrier per tile. exp2-domain defer-max softmax (scale pre-folded in Q);
// row-sum via ones-MFMA. grid = 512 (16 pairs x 32 bh).
// ---------------------------------------------------------------------------
__device__ __forceinline__ int psw(int row) {
  return (((row & 7) ^ ((row >> 3) & 7))) << 4;
}

__global__ __launch_bounds__(256, 2)
void attn_causal5(const __bf16* __restrict__ qkv, const __bf16* __restrict__ vt,
                  __bf16* __restrict__ yb) {
  __shared__ __align__(16) char Kbuf[2][8192];   // K[kv][d], chunk-swizzled
  __shared__ __align__(16) char Vbuf[2][8192];   // Vt[d][kv], chunk-swizzled
  __shared__ __align__(16) char Pbuf[4][4096];   // per-wave P[32][64], psw-swizzled

  const int tid = threadIdx.x;
  const int lane = tid & 63, w = tid >> 6;
  const int L = blockIdx.x;
  const int bh = L & 31, p = L >> 5;             // p in 0..15
  const int cA = p, cB = 31 - p;
  const int b = bh >> 4, h = bh & 15;
  const size_t rowbase = (size_t)b * TT;
  const int fr = lane & 15, g = lane >> 4;
  const int q0A = cA * 64 + w * 16;
  const int q0B = cB * 64 + w * 16;

  // Q fragments (already scaled by SCL at gemm1 epilogue)
  bf16x8 qfA[2], qfB[2];
#pragma unroll
  for (int kc = 0; kc < 2; kc++) {
    qfA[kc] = *(const bf16x8*)(qkv + (rowbase + q0A + fr) * QKVN + h * HD + kc * 32 + g * 8);
    qfB[kc] = *(const bf16x8*)(qkv + (rowbase + q0B + fr) * QKVN + h * HD + kc * 32 + g * 8);
  }

  bf16x8 ones;
#pragma unroll
  for (int j = 0; j < 8; j++) ones[j] = (__bf16)1.0f;

  f32x4 oA[4], oB[4], laccA, laccB;
  float mA[4], mB[4];
#pragma unroll
  for (int n = 0; n < 4; n++)
#pragma unroll
    for (int r = 0; r < 4; r++) { oA[n][r] = 0.0f; oB[n][r] = 0.0f; }
#pragma unroll
  for (int r = 0; r < 4; r++) { laccA[r] = 0.0f; laccB[r] = 0.0f; mA[r] = -1e30f; mB[r] = -1e30f; }

  auto stageK = [&](int kt, int buf) {
#pragma unroll
    for (int i = 0; i < 2; i++) {
      const int c = tid + i * 256;
      const int row = c >> 3;
      const int c16 = (c & 7) ^ (row & 7);
      gload_lds16(qkv + (rowbase + kt * 64 + row) * QKVN + EMB + h * HD + c16 * 8,
                  Kbuf[buf] + c * 16);
    }
  };
  auto stageV = [&](int kt, int buf) {
#pragma unroll
    for (int i = 0; i < 2; i++) {
      const int c = tid + i * 256;
      const int row = c >> 3;
      const int c16 = (c & 7) ^ (row & 7);
      gload_lds16(vt + ((size_t)bh * HD + row) * TT + kt * 64 + c16 * 8,
                  Vbuf[buf] + c * 16);
    }
  };

  stageK(0, 0);
  stageV(0, 0);
  __syncthreads();

  int cur = 0;
  for (int kt = 0; kt <= cB; kt++) {
    if (kt < cB) { stageK(kt + 1, cur ^ 1); stageV(kt + 1, cur ^ 1); }

    const int kv0 = kt * 64;
    // shared K / V fragments from swizzled LDS (feed both row-groups)
    bf16x8 kf[4][2], vb[4][2];
#pragma unroll
    for (int n = 0; n < 4; n++)
#pragma unroll
      for (int kc = 0; kc < 2; kc++) {
        const int row = n * 16 + fr;
        const int sw = (((kc << 2) | g) ^ (row & 7)) * 16;
        kf[n][kc] = *(const bf16x8*)(Kbuf[cur] + row * 128 + sw);
        vb[n][kc] = *(const bf16x8*)(Vbuf[cur] + row * 128 + sw);
      }

    // per-row-group compute (no runtime group index -> no scratch)
    auto process = [&](bf16x8 (&qf)[2], f32x4 (&o)[4], f32x4 &lacc, float (&m)[4],
                       int q0g, int cg, int prow) {
      f32x4 s[4];
#pragma unroll
      for (int n = 0; n < 4; n++) {
#pragma unroll
        for (int r = 0; r < 4; r++) s[n][r] = 0.0f;
#pragma unroll
        for (int kc = 0; kc < 2; kc++)
          s[n] = __builtin_amdgcn_mfma_f32_16x16x32_bf16(qf[kc], kf[n][kc], s[n], 0, 0, 0);
      }
      if (kt == cg) {                        // causal mask on diagonal tile
#pragma unroll
        for (int n = 0; n < 4; n++)
#pragma unroll
          for (int r = 0; r < 4; r++) {
            const int qg = q0g + g * 4 + r;
            const int kg = kv0 + n * 16 + fr;
            if (kg > qg) s[n][r] = -1e30f;
          }
      }
      float pm[4];
#pragma unroll
      for (int r = 0; r < 4; r++)
        pm[r] = fmaxf(fmaxf(s[0][r], s[1][r]), fmaxf(s[2][r], s[3][r]));
      const bool ok = (pm[0] <= m[0] + THR) && (pm[1] <= m[1] + THR) &&
                      (pm[2] <= m[2] + THR) && (pm[3] <= m[3] + THR);
      if (!__all(ok)) {
#pragma unroll
        for (int r = 0; r < 4; r++) {
          float rm = pm[r];
#pragma unroll
          for (int d = 1; d < 16; d <<= 1) rm = fmaxf(rm, __shfl_xor(rm, d, 16));
          const float nm = fmaxf(m[r], rm);
          const float f = exp2f(m[r] - nm);
          m[r] = nm;
          lacc[r] *= f;
#pragma unroll
          for (int n = 0; n < 4; n++) o[n][r] *= f;
        }
      }
#pragma unroll
      for (int n = 0; n < 4; n++)
#pragma unroll
        for (int r = 0; r < 4; r++) {
          const float e = exp2f(s[n][r] - m[r]);
          const int row = prow + g * 4 + r;
          *(__bf16*)(Pbuf[w] + row * 128 + (((n * 16 + fr) * 2) ^ psw(row))) = (__bf16)e;
        }
      bf16x8 pa[2];
#pragma unroll
      for (int kc = 0; kc < 2; kc++) {
        const int row = prow + fr;
        pa[kc] = *(const bf16x8*)(Pbuf[w] + row * 128 + ((kc * 64 + g * 16) ^ psw(row)));
      }
#pragma unroll
      for (int kc = 0; kc < 2; kc++) {
        lacc = __builtin_amdgcn_mfma_f32_16x16x32_bf16(pa[kc], ones, lacc, 0, 0, 0);
#pragma unroll
        for (int n = 0; n < 4; n++)
          o[n] = __builtin_amdgcn_mfma_f32_16x16x32_bf16(pa[kc], vb[n][kc], o[n], 0, 0, 0);
      }
    };

    process(qfB, oB, laccB, mB, q0B, cB, 16);    // group B: always active (kt <= cB)
    if (kt <= cA) process(qfA, oA, laccA, mA, q0A, cA, 0);

    __syncthreads();
    cur ^= 1;
  }

  // normalize + store both groups
#pragma unroll
  for (int r = 0; r < 4; r++) {
    const float invA = __builtin_amdgcn_rcpf(laccA[r]);
    const float invB = __builtin_amdgcn_rcpf(laccB[r]);
#pragma unroll
    for (int n = 0; n < 4; n++) {
      const int d = n * 16 + fr;
      yb[(rowbase + q0A + g * 4 + r) * EMB + h * HD + d] = (__bf16)(oA[n][r] * invA);
      yb[(rowbase + q0B + g * 4 + r) * EMB + h * HD + d] = (__bf16)(oB[n][r] * invB);
    }
  }
}

extern "C" void kernel_launch(void* const* d_in, const int* in_sizes, int n_in,
                              void* d_out, int out_size, void* d_ws, size_t ws_size,
                              hipStream_t stream) {
  const float* x     = (const float*)d_in[0];
  const float* w_qkv = (const float*)d_in[1];
  const float* w_out = (const float*)d_in[2];
  float* out = (float*)d_out;

  char* ws = (char*)d_ws;
  __bf16* xb    = (__bf16*)(ws);                 // reused as Vt after gemm1
  __bf16* wqkvb = (__bf16*)(ws + (8ull  << 20));
  __bf16* wob   = (__bf16*)(ws + (14ull << 20));
  __bf16* qkvb  = (__bf16*)(ws + (16ull << 20));
  __bf16* yb    = (__bf16*)(ws + (40ull << 20));
  __bf16* vtb   = xb;

  cvt_all<<<4096, 256, 0, stream>>>(x, w_qkv, w_out, xb, wqkvb, wob);
  gemm_bt<1, 1><<<dim3(QKVN / 128, NROWS / 128), 256, 0, stream>>>(xb, wqkvb, qkvb, NROWS, QKVN, EMB);
  vtrans<<<dim3(TT / 64, 32), 256, 0, stream>>>(qkvb, vtb);
  attn_causal5<<<512, 256, 0, stream>>>(qkvb, vtb, yb);
  gemm_bt<0, 0><<<dim3(EMB / 128, NROWS / 128), 256, 0, stream>>>(yb, wob, out, NROWS, EMB, EMB);
}

// Round 6
// 115.244 us; speedup vs baseline: 1.0259x; 1.0259x over previous
//
#include <hip/hip_runtime.h>
#include <hip/hip_bf16.h>
#include <cstdint>

// ---------------------------------------------------------------------------
// Fused causal self-attention block (B=2, T=2048, C=1024, H=16, Dh=64), fp32 in/out.
// cvt fp32->bf16 -> QKV GEMM (Q pre-scaled) -> V-transpose -> causal flash attn -> out GEMM.
// Workspace (48MB):
//   xb/Vt @ 0     8 MB   bf16 x [4096][1024]; REUSED after gemm1 as Vt [32][64][2048]
//   wqkvb @ 8 MB  6 MB   bf16 w_qkv [3072][1024]
//   wob   @ 14MB  2 MB   bf16 w_out [1024][1024]
//   qkvb  @ 16MB 24 MB   bf16 qkv [4096][3072] (Q|K|V; Q scaled by 0.125*log2e)
//   yb    @ 40MB  8 MB   bf16 attn out [4096][1024]
// ---------------------------------------------------------------------------

typedef __bf16 bf16x8 __attribute__((ext_vector_type(8)));
typedef __bf16 bf16x2 __attribute__((ext_vector_type(2)));
typedef float  f32x4  __attribute__((ext_vector_type(4)));

#define EMB   1024
#define HEADS 16
#define HD    64
#define TT    2048
#define NROWS 4096
#define QKVN  3072
#define SCL   0.18033688f   /* 0.125 * log2(e): folded into Q at gemm1 epilogue */
#define THR   11.0f         /* defer-max threshold, log2 units */

// ---- fused fp32 -> bf16 (8 elems / thread, 3 arrays in one launch) ----
__global__ void cvt_all(const float* __restrict__ x, const float* __restrict__ wq,
                        const float* __restrict__ wo, __bf16* __restrict__ xb,
                        __bf16* __restrict__ wqb, __bf16* __restrict__ wob) {
  const int bid = blockIdx.x;
  const float* in; __bf16* out; int i;
  if (bid < 2048)      { in = x;  out = xb;  i = bid * 256 + threadIdx.x; }
  else if (bid < 3584) { in = wq; out = wqb; i = (bid - 2048) * 256 + threadIdx.x; }
  else                 { in = wo; out = wob; i = (bid - 3584) * 256 + threadIdx.x; }
  const float4* p = (const float4*)in + (size_t)i * 2;
  float4 a = p[0], b = p[1];
  bf16x8 o;
  o[0] = (__bf16)a.x; o[1] = (__bf16)a.y; o[2] = (__bf16)a.z; o[3] = (__bf16)a.w;
  o[4] = (__bf16)b.x; o[5] = (__bf16)b.y; o[6] = (__bf16)b.z; o[7] = (__bf16)b.w;
  *((bf16x8*)out + i) = o;
}

__device__ __forceinline__ void gload_lds16(const void* g, void* l) {
  __builtin_amdgcn_global_load_lds(
      (const __attribute__((address_space(1))) void*)(uintptr_t)g,
      (__attribute__((address_space(3))) void*)(uint32_t)(uintptr_t)l,
      16, 0, 0);
}

// ---- GEMM: C[M,N] = A[M,K] * Bm[N,K]^T (m97 structure + XCD swizzle) ----
template <int OUT_BF16, int SCALE_Q>
__global__ __launch_bounds__(256, 2)
void gemm_bt(const __bf16* __restrict__ A, const __bf16* __restrict__ Bm,
             void* __restrict__ Cout, int M, int N, int K) {
  __shared__ __align__(16) __bf16 As[128 * 32];
  __shared__ __align__(16) __bf16 Bs[128 * 32];
  const int tid  = threadIdx.x;
  const int lane = tid & 63;
  const int wid  = tid >> 6;
  const int wr = wid >> 1, wc = wid & 1;
  const int nwg = gridDim.x * gridDim.y;
  int flat = blockIdx.y * gridDim.x + blockIdx.x;
  flat = (flat & 7) * (nwg >> 3) + (flat >> 3);
  const int brow = (flat / gridDim.x) * 128;
  const int bcol = (flat % gridDim.x) * 128;
  const int fr = lane & 15, g = lane >> 4;

  f32x4 acc[4][4];
#pragma unroll
  for (int m = 0; m < 4; m++)
#pragma unroll
    for (int n = 0; n < 4; n++)
#pragma unroll
      for (int r = 0; r < 4; r++) acc[m][n][r] = 0.0f;

  const int c0 = tid, c1 = tid + 256;
  for (int k0 = 0; k0 < K; k0 += 32) {
    __syncthreads();
    gload_lds16(A  + (size_t)(brow + (c0 >> 2)) * K + k0 + (c0 & 3) * 8, (char*)As + c0 * 16);
    gload_lds16(A  + (size_t)(brow + (c1 >> 2)) * K + k0 + (c1 & 3) * 8, (char*)As + c1 * 16);
    gload_lds16(Bm + (size_t)(bcol + (c0 >> 2)) * K + k0 + (c0 & 3) * 8, (char*)Bs + c0 * 16);
    gload_lds16(Bm + (size_t)(bcol + (c1 >> 2)) * K + k0 + (c1 & 3) * 8, (char*)Bs + c1 * 16);
    __syncthreads();

    bf16x8 af[4], bfr[4];
#pragma unroll
    for (int m = 0; m < 4; m++)
      af[m] = *(const bf16x8*)((const char*)As + (wr * 64 + m * 16 + fr) * 64 + g * 16);
#pragma unroll
    for (int n = 0; n < 4; n++)
      bfr[n] = *(const bf16x8*)((const char*)Bs + (wc * 64 + n * 16 + fr) * 64 + g * 16);
#pragma unroll
    for (int m = 0; m < 4; m++)
#pragma unroll
      for (int n = 0; n < 4; n++)
        acc[m][n] = __builtin_amdgcn_mfma_f32_16x16x32_bf16(af[m], bfr[n], acc[m][n], 0, 0, 0);
  }

  const float qscale = (SCALE_Q && bcol < EMB) ? SCL : 1.0f;
  const int rbase = brow + wr * 64 + g * 4;
  const int cbase = bcol + wc * 64 + fr;
#pragma unroll
  for (int m = 0; m < 4; m++)
#pragma unroll
    for (int n = 0; n < 4; n++) {
      const int col = cbase + n * 16;
#pragma unroll
      for (int r = 0; r < 4; r++) {
        const int row = rbase + m * 16 + r;
        const float v = acc[m][n][r] * qscale;
        if (OUT_BF16) ((__bf16*)Cout)[(size_t)row * N + col] = (__bf16)v;
        else          ((float*)Cout)[(size_t)row * N + col]  = v;
      }
    }
}

// ---- V transpose: qkv [4096][3072] (V cols) -> Vt [32 bh][64 d][2048 t] ----
__global__ __launch_bounds__(256)
void vtrans(const __bf16* __restrict__ qkv, __bf16* __restrict__ vt) {
  __shared__ __bf16 tile[64][66];
  const int tt = blockIdx.x;
  const int bh = blockIdx.y;
  const int b = bh >> 4, h = bh & 15;
  const int tid = threadIdx.x;
  const int tl = tid >> 2, dq = (tid & 3) * 16;
  const __bf16* src = qkv + ((size_t)(b * TT + tt * 64 + tl)) * QKVN + 2 * EMB + h * HD + dq;
  bf16x8 v0 = *(const bf16x8*)src;
  bf16x8 v1 = *(const bf16x8*)(src + 8);
#pragma unroll
  for (int u = 0; u < 4; u++) {
    *(bf16x2*)&tile[tl][dq + 2 * u]     = bf16x2{v0[2 * u], v0[2 * u + 1]};
    *(bf16x2*)&tile[tl][dq + 8 + 2 * u] = bf16x2{v1[2 * u], v1[2 * u + 1]};
  }
  __syncthreads();
  const int d = tid >> 2, tc = (tid & 3) * 16;
  bf16x8 o0, o1;
#pragma unroll
  for (int j = 0; j < 8; j++) { o0[j] = tile[tc + j][d]; o1[j] = tile[tc + 8 + j][d]; }
  __bf16* dst = vt + ((size_t)bh * HD + d) * TT + tt * 64 + tc;
  *(bf16x8*)dst = o0;
  *(bf16x8*)(dst + 8) = o1;
}

// ---------------------------------------------------------------------------
// Causal flash attention v6 = v4 per-tile code + LPT scheduling.
//   - LDS padded to 48KB (Pbuf 4x4096) -> exactly 3 blocks/CU resident,
//     leaving a 256-block backfill queue (1024 blocks / 341 slots).
//   - chunk = 31 - (L>>5): longest blocks dispatch FIRST (LPT), shortest
//     backfill last -> CU makespan ~22 tile-units vs ~32 before.
//   - bh = L&31 keeps XCD = bh%8 L2 locality.
// Per-tile pipeline identical to v4: K and Vt direct gload_lds (source-
// swizzled, linear dest), double-buffered, one barrier per tile, exp2-domain
// defer-max softmax (scale pre-folded into Q), row-sum via ones-MFMA.
// ---------------------------------------------------------------------------
__device__ __forceinline__ int psw(int row) {
  return (((row & 7) ^ ((row >> 3) & 7))) << 4;
}

__global__ __launch_bounds__(256, 3)
void attn_causal6(const __bf16* __restrict__ qkv, const __bf16* __restrict__ vt,
                  __bf16* __restrict__ yb) {
  __shared__ __align__(16) char Kbuf[2][8192];   // K[kv][d], chunk-swizzled
  __shared__ __align__(16) char Vbuf[2][8192];   // Vt[d][kv], chunk-swizzled
  __shared__ __align__(16) char Pbuf[4][4096];   // per-wave P[16][64] (padded to cap 3 blocks/CU)

  const int tid = threadIdx.x;
  const int lane = tid & 63, w = tid >> 6;
  const int L = blockIdx.x;
  const int bh = L & 31;
  const int chunk = 31 - (L >> 5);               // LPT: longest first
  const int b = bh >> 4, h = bh & 15;
  const size_t rowbase = (size_t)b * TT;
  const int q0 = chunk * 64 + w * 16;
  const int fr = lane & 15, g = lane >> 4;
  const int ntiles = chunk + 1;

  bf16x8 qf[2];
#pragma unroll
  for (int kc = 0; kc < 2; kc++)
    qf[kc] = *(const bf16x8*)(qkv + (rowbase + q0 + fr) * QKVN + h * HD + kc * 32 + g * 8);

  bf16x8 ones;
#pragma unroll
  for (int j = 0; j < 8; j++) ones[j] = (__bf16)1.0f;

  f32x4 o[4];
  f32x4 lacc;
  float m[4];
#pragma unroll
  for (int n = 0; n < 4; n++)
#pragma unroll
    for (int r = 0; r < 4; r++) o[n][r] = 0.0f;
#pragma unroll
  for (int r = 0; r < 4; r++) { lacc[r] = 0.0f; m[r] = -1e30f; }

  auto stageK = [&](int kt, int buf) {
#pragma unroll
    for (int i = 0; i < 2; i++) {
      const int c = tid + i * 256;
      const int row = c >> 3;
      const int c16 = (c & 7) ^ (row & 7);
      gload_lds16(qkv + (rowbase + kt * 64 + row) * QKVN + EMB + h * HD + c16 * 8,
                  Kbuf[buf] + c * 16);
    }
  };
  auto stageV = [&](int kt, int buf) {
#pragma unroll
    for (int i = 0; i < 2; i++) {
      const int c = tid + i * 256;
      const int row = c >> 3;
      const int c16 = (c & 7) ^ (row & 7);
      gload_lds16(vt + ((size_t)bh * HD + row) * TT + kt * 64 + c16 * 8,
                  Vbuf[buf] + c * 16);
    }
  };

  stageK(0, 0);
  stageV(0, 0);
  __syncthreads();

  int cur = 0;
  for (int kt = 0; kt < ntiles; kt++) {
    if (kt + 1 < ntiles) { stageK(kt + 1, cur ^ 1); stageV(kt + 1, cur ^ 1); }

    const int kv0 = kt * 64;
    bf16x8 kf[4][2];
#pragma unroll
    for (int n = 0; n < 4; n++)
#pragma unroll
      for (int kc = 0; kc < 2; kc++) {
        const int row = n * 16 + fr;
        kf[n][kc] = *(const bf16x8*)(Kbuf[cur] + row * 128 + (((kc << 2) | g) ^ (row & 7)) * 16);
      }
    f32x4 s[4];
#pragma unroll
    for (int n = 0; n < 4; n++) {
#pragma unroll
      for (int r = 0; r < 4; r++) s[n][r] = 0.0f;
#pragma unroll
      for (int kc = 0; kc < 2; kc++)
        s[n] = __builtin_amdgcn_mfma_f32_16x16x32_bf16(qf[kc], kf[n][kc], s[n], 0, 0, 0);
    }
    if (kt == chunk) {                    // causal mask only on diagonal tile
#pragma unroll
      for (int n = 0; n < 4; n++)
#pragma unroll
        for (int r = 0; r < 4; r++) {
          const int qg = q0 + g * 4 + r;
          const int kg = kv0 + n * 16 + fr;
          if (kg > qg) s[n][r] = -1e30f;
        }
    }
    float pm[4];
#pragma unroll
    for (int r = 0; r < 4; r++)
      pm[r] = fmaxf(fmaxf(s[0][r], s[1][r]), fmaxf(s[2][r], s[3][r]));
    const bool ok = (pm[0] <= m[0] + THR) && (pm[1] <= m[1] + THR) &&
                    (pm[2] <= m[2] + THR) && (pm[3] <= m[3] + THR);
    if (!__all(ok)) {
#pragma unroll
      for (int r = 0; r < 4; r++) {
        float rm = pm[r];
#pragma unroll
        for (int d = 1; d < 16; d <<= 1) rm = fmaxf(rm, __shfl_xor(rm, d, 16));
        const float nm = fmaxf(m[r], rm);
        const float f = exp2f(m[r] - nm);
        m[r] = nm;
        lacc[r] *= f;
#pragma unroll
        for (int n = 0; n < 4; n++) o[n][r] *= f;
      }
    }
#pragma unroll
    for (int n = 0; n < 4; n++)
#pragma unroll
      for (int r = 0; r < 4; r++) {
        const float e = exp2f(s[n][r] - m[r]);
        const int row = g * 4 + r;
        *(__bf16*)(Pbuf[w] + row * 128 + (((n * 16 + fr) * 2) ^ psw(row))) = (__bf16)e;
      }
    bf16x8 pa[2];
#pragma unroll
    for (int kc = 0; kc < 2; kc++)
      pa[kc] = *(const bf16x8*)(Pbuf[w] + fr * 128 + ((kc * 64 + g * 16) ^ psw(fr)));
    bf16x8 vb[4][2];
#pragma unroll
    for (int n = 0; n < 4; n++)
#pragma unroll
      for (int kc = 0; kc < 2; kc++) {
        const int row = n * 16 + fr;
        vb[n][kc] = *(const bf16x8*)(Vbuf[cur] + row * 128 + (((kc << 2) | g) ^ (row & 7)) * 16);
      }
#pragma unroll
    for (int kc = 0; kc < 2; kc++) {
      lacc = __builtin_amdgcn_mfma_f32_16x16x32_bf16(pa[kc], ones, lacc, 0, 0, 0);
#pragma unroll
      for (int n = 0; n < 4; n++)
        o[n] = __builtin_amdgcn_mfma_f32_16x16x32_bf16(pa[kc], vb[n][kc], o[n], 0, 0, 0);
    }

    __syncthreads();
    cur ^= 1;
  }

#pragma unroll
  for (int n = 0; n < 4; n++)
#pragma unroll
    for (int r = 0; r < 4; r++) {
      const int q = q0 + g * 4 + r;
      const int d = n * 16 + fr;
      yb[(rowbase + q) * EMB + h * HD + d] = (__bf16)(o[n][r] / lacc[r]);
    }
}

extern "C" void kernel_launch(void* const* d_in, const int* in_sizes, int n_in,
                              void* d_out, int out_size, void* d_ws, size_t ws_size,
                              hipStream_t stream) {
  const float* x     = (const float*)d_in[0];
  const float* w_qkv = (const float*)d_in[1];
  const float* w_out = (const float*)d_in[2];
  float* out = (float*)d_out;

  char* ws = (char*)d_ws;
  __bf16* xb    = (__bf16*)(ws);                 // reused as Vt after gemm1
  __bf16* wqkvb = (__bf16*)(ws + (8ull  << 20));
  __bf16* wob   = (__bf16*)(ws + (14ull << 20));
  __bf16* qkvb  = (__bf16*)(ws + (16ull << 20));
  __bf16* yb    = (__bf16*)(ws + (40ull << 20));
  __bf16* vtb   = xb;

  cvt_all<<<4096, 256, 0, stream>>>(x, w_qkv, w_out, xb, wqkvb, wob);
  gemm_bt<1, 1><<<dim3(QKVN / 128, NROWS / 128), 256, 0, stream>>>(xb, wqkvb, qkvb, NROWS, QKVN, EMB);
  vtrans<<<dim3(TT / 64, 32), 256, 0, stream>>>(qkvb, vtb);
  attn_causal6<<<1024, 256, 0, stream>>>(qkvb, vtb, yb);
  gemm_bt<0, 0><<<dim3(EMB / 128, NROWS / 128), 256, 0, stream>>>(yb, wob, out, NROWS, EMB, EMB);
}